// Round 6
// baseline (140.846 us; speedup 1.0000x reference)
//
#include <hip/hip_runtime.h>
#include <stdint.h>
#include <stddef.h>

#define NB_HEAD 8
#define DHEAD   32
#define B_      4
#define S_      2046
#define N_      2048
#define M_      1024
#define D_      256

typedef __attribute__((ext_vector_type(8))) short short8;
typedef __attribute__((ext_vector_type(4))) float f32x4;

__device__ __forceinline__ void bf2x2(uint32_t u, float& lo, float& hi) {
    union { uint32_t i; float f; } a, b;
    a.i = u << 16;
    b.i = u & 0xffff0000u;
    lo = a.f; hi = b.f;
}
__device__ __forceinline__ float bf2f(uint16_t u) {
    union { uint32_t i; float f; } v; v.i = ((uint32_t)u) << 16; return v.f;
}
__device__ __forceinline__ uint16_t f2bf(float f) {
    union { float f; uint32_t i; } v; v.f = f;
    uint32_t u = v.i;
    u += 0x7fffu + ((u >> 16) & 1u);   // RNE
    return (uint16_t)(u >> 16);
}
__device__ __forceinline__ short8 ld_frag(const uint16_t* p) {
    union { uint4 u; short8 s; } v;
    v.u = *(const uint4*)p;
    return v.s;
}
__device__ __forceinline__ void unp8(short8 v, float* f) {
    union { short8 s; uint32_t u[4]; } x; x.s = v;
    #pragma unroll
    for (int k = 0; k < 4; ++k) bf2x2(x.u[k], f[2*k], f[2*k+1]);
}
// pack top-16 bits of two fp32 bit patterns into one dword (hi<<16 | lo)
__device__ __forceinline__ uint32_t pkbf(uint32_t hi, uint32_t lo) {
    return __builtin_amdgcn_perm(hi, lo, 0x07060302u);
}

// ---------------------------------------------------------------------------
// Kernel 0: Wt[c][k] = bf16(W[k][c]), one-shot 256x256 transpose.
// ---------------------------------------------------------------------------
__global__ __launch_bounds__(256) void wt_kernel(
    const float* __restrict__ W, uint16_t* __restrict__ Wt)
{
    const int t  = blockIdx.x * 256 + threadIdx.x;
    const int c  = t >> 6;
    const int k0 = (t & 63) * 4;
    union { uint16_t h[4]; uint2 u; } v;
    #pragma unroll
    for (int kk = 0; kk < 4; ++kk)
        v.h[kk] = f2bf(W[(size_t)(k0 + kk) * D_ + c]);
    *(uint2*)(Wt + (size_t)c * D_ + k0) = v.u;
}

// ---------------------------------------------------------------------------
// Kernel 1: MFMA projection, 1024 blocks = 128 row-groups(64) x 8 col-groups(32).
//   Wave = 16 rows x 32 cols = 2 nt x 8 kc MFMAs. Epilogue stages the block's
//   64x32 bf16 tile in LDS, then writes BOTH layouts coalesced:
//     qkv [p][i][d]   (row-major)
//     qkvT[p][d][pos] pos = within-32 perm matching attn's P^T k-slot order.
//   Block's col-group == head (c0 = cg*32), so each block feeds exactly 2 p's.
// ---------------------------------------------------------------------------
__global__ __launch_bounds__(256) void proj_kernel(
    const float* __restrict__ x, const uint16_t* __restrict__ Wt,
    const float* __restrict__ bias,
    uint16_t* __restrict__ qkv, uint16_t* __restrict__ qkvT)
{
    __shared__ uint16_t Tl[64 * 40];              // stride 40 el = 80 B
    const int tid  = threadIdx.x;
    const int w    = tid >> 6;
    const int lane = tid & 63;
    const int q    = lane >> 4;
    const int n16  = lane & 15;
    const int rg   = blockIdx.x >> 3;             // 0..127
    const int cg   = blockIdx.x & 7;              // 0..7  (== head)
    const int n0   = rg * 64;
    const int b    = n0 >> 11;
    const int nnb  = n0 & 2047;
    const int c0   = cg * 32;

    const f32x4 kZ = {0.f, 0.f, 0.f, 0.f};
    f32x4 acc[2];
    acc[0] = kZ; acc[1] = kZ;

    const int nrow = nnb + w * 16 + n16;
    const bool ok  = (nrow < S_);
    const float* xrow = x + ((size_t)b * S_ + (ok ? nrow : 0)) * D_;

    #pragma unroll
    for (int kc = 0; kc < 8; ++kc) {
        short8 A;
        if (ok) {
            const uint32_t* xp2 = (const uint32_t*)(xrow + kc * 32 + q * 8);
            uint4 f0 = *(const uint4*)xp2;
            uint4 f1 = *(const uint4*)(xp2 + 4);
            union { uint32_t u[4]; short8 s; } av;
            av.u[0] = pkbf(f0.y + 0x8000u, f0.x + 0x8000u);
            av.u[1] = pkbf(f0.w + 0x8000u, f0.z + 0x8000u);
            av.u[2] = pkbf(f1.y + 0x8000u, f1.x + 0x8000u);
            av.u[3] = pkbf(f1.w + 0x8000u, f1.z + 0x8000u);
            A = av.s;
        } else {
            A = short8{0,0,0,0,0,0,0,0};
        }
        #pragma unroll
        for (int nt = 0; nt < 2; ++nt) {
            short8 Bf = ld_frag(Wt + (size_t)(c0 + nt * 16 + n16) * D_ + kc * 32 + q * 8);
            acc[nt] = __builtin_amdgcn_mfma_f32_16x16x32_bf16(A, Bf, acc[nt], 0, 0, 0);
        }
    }

    #pragma unroll
    for (int nt = 0; nt < 2; ++nt) {
        const float bv = bias[c0 + nt * 16 + n16];
        #pragma unroll
        for (int r = 0; r < 4; ++r)
            Tl[(w * 16 + q * 4 + r) * 40 + nt * 16 + n16] = f2bf(acc[nt][r] + bv);
    }
    __syncthreads();

    // ---- write phase: wave w -> parity rr = w&1, half = w>>1 ----
    const int rr   = w & 1;
    const int half = w >> 1;
    const int pglob = (b * NB_HEAD + cg) * 2 + rr;
    const int ibase = nnb >> 1;                   // multiple of 32
    uint16_t* qk = qkv  + (size_t)pglob * (M_ * DHEAD);
    uint16_t* qt = qkvT + (size_t)pglob * (M_ * DHEAD);

    {   // qkv: lane -> (il = half*16 + lane>>2, d0 = (lane&3)*8): 16 B/lane
        const int il = half * 16 + (lane >> 2);
        const int d0 = (lane & 3) * 8;
        uint4 v = *(const uint4*)(Tl + (2 * il + rr) * 40 + d0);
        *(uint4*)(qk + (size_t)(ibase + il) * DHEAD + d0) = v;
    }
    {   // qkvT: lane -> (d = half*16 + lane>>2, pos0 = (lane&3)*8): 16 B/lane
        const int d  = half * 16 + (lane >> 2);
        const int p0 = (lane & 3) * 8;
        uint32_t pk[4];
        #pragma unroll
        for (int t = 0; t < 8; ++t) {
            const int pos = p0 + t;
            const int il = (((pos >> 2) & 1) << 4) | (((pos >> 3) & 3) << 2) | (pos & 3);
            const uint32_t vv = Tl[(2 * il + rr) * 40 + d];
            if (t & 1) pk[t >> 1] |= vv << 16; else pk[t >> 1] = vv;
        }
        *(uint4*)(qt + (size_t)d * M_ + ibase + p0) = *(uint4*)&pk[0];
    }
}

// ---------------------------------------------------------------------------
// Kernel 2: MFMA flash attention, transposed scores, zero LDS, no barriers.
//   1024 blocks = 64 problems x 16 chunks(64 rows); 4 waves x 16 rows
//   -> 16 waves/CU (4/SIMD) for latency hiding.
//   Scores: St = mfma(A = X_j frag, B = Q frag) -> lane(q,n16): P[j=g*16+q*4+r][i=n16]
//   PV:     O^T = mfma(A = qkvT row-d frag, B = P^T packed in-register)
//   XCD swizzle: bid&7 selects XCD slot; all 16 chunks of a problem share it.
// ---------------------------------------------------------------------------
__global__ __launch_bounds__(256) void attn_kernel(
    const uint16_t* __restrict__ qkv, const uint16_t* __restrict__ qkvT,
    float* __restrict__ out)
{
    const float SCL = 0.17677669529663687f * 1.4426950408889634f; // 1/sqrt(32)*log2(e)
    const int tid  = threadIdx.x;
    const int w    = tid >> 6;
    const int lane = tid & 63;
    const int q    = lane >> 4;
    const int n16  = lane & 15;
    const int bid  = blockIdx.x;
    const int p     = ((bid & 7) << 3) | ((bid >> 3) & 7);
    const int chunk = bid >> 6;                   // 0..15
    const uint16_t* Xp = qkv  + (size_t)p * (M_ * DHEAD);
    const uint16_t* Xt = qkvT + (size_t)p * (M_ * DHEAD);

    const int rbase = chunk * 64 + w * 16;
    const f32x4 kZ = {0.f, 0.f, 0.f, 0.f};

    short8 Q0 = ld_frag(Xp + (size_t)(rbase + n16) * DHEAD + q * 8);

    f32x4 Ot[2];                       // [h]: O^T[d = h*16+q*4+r][i = n16]
    Ot[0] = kZ; Ot[1] = kZ;
    float Lp = 0.f;

    short8 Bf[4], XF[2][2];
    #pragma unroll
    for (int g = 0; g < 4; ++g)
        Bf[g] = ld_frag(Xp + (size_t)(g * 16 + n16) * DHEAD + q * 8);
    #pragma unroll
    for (int h = 0; h < 2; ++h)
        #pragma unroll
        for (int c = 0; c < 2; ++c)
            XF[h][c] = ld_frag(Xt + (size_t)(h * 16 + n16) * M_ + c * 32 + q * 8);

    for (int tile = 0; tile < 16; ++tile) {
        f32x4 S[4];
        #pragma unroll
        for (int g = 0; g < 4; ++g)
            S[g] = __builtin_amdgcn_mfma_f32_16x16x32_bf16(Bf[g], Q0, kZ, 0, 0, 0);

        // prefetch next tile (wrap on last)
        const int jb2 = ((tile + 1) & 15) * 64;
        short8 Bn[4], XFn[2][2];
        #pragma unroll
        for (int g = 0; g < 4; ++g)
            Bn[g] = ld_frag(Xp + (size_t)(jb2 + g * 16 + n16) * DHEAD + q * 8);
        #pragma unroll
        for (int h = 0; h < 2; ++h)
            #pragma unroll
            for (int c = 0; c < 2; ++c)
                XFn[h][c] = ld_frag(Xt + (size_t)(h * 16 + n16) * M_ + jb2 + c * 32 + q * 8);

        // fixed-max softmax numerators (round-half-up to bf16 via +0x8000 + perm)
        uint32_t t[4][4];
        float rs = 0.f;
        #pragma unroll
        for (int g = 0; g < 4; ++g)
            #pragma unroll
            for (int r = 0; r < 4; ++r) {
                float e = exp2f(S[g][r] * SCL);
                t[g][r] = __float_as_uint(e) + 0x8000u;
                rs += e;                          // fp32 L (≈ consistent, err ~1e-4 rel)
            }
        Lp += rs;
        #pragma unroll
        for (int c = 0; c < 2; ++c) {
            union { uint32_t u[4]; short8 s; } bp;
            bp.u[0] = pkbf(t[2*c][1],   t[2*c][0]);
            bp.u[1] = pkbf(t[2*c][3],   t[2*c][2]);
            bp.u[2] = pkbf(t[2*c+1][1], t[2*c+1][0]);
            bp.u[3] = pkbf(t[2*c+1][3], t[2*c+1][2]);
            Ot[0] = __builtin_amdgcn_mfma_f32_16x16x32_bf16(XF[0][c], bp.s, Ot[0], 0, 0, 0);
            Ot[1] = __builtin_amdgcn_mfma_f32_16x16x32_bf16(XF[1][c], bp.s, Ot[1], 0, 0, 0);
        }
        #pragma unroll
        for (int g = 0; g < 4; ++g) Bf[g] = Bn[g];
        #pragma unroll
        for (int h = 0; h < 2; ++h) {
            XF[h][0] = XFn[h][0]; XF[h][1] = XFn[h][1];
        }
    }

    // ---- reduce L over the 4 q-quads (lane bits 4,5) ----
    Lp += __shfl_xor(Lp, 16, 64);
    Lp += __shfl_xor(Lp, 32, 64);

    // ---- epilogue: 3 local extras per row + normalize + store ----
    const int rpar  = p & 1;
    const int hh    = (p >> 1) & 7;
    const int bglob = p >> 4;

    {
        const int i = rbase + n16;
        float qf[8];
        unp8(Q0, qf);
        const int im1 = max(i - 1, 0);
        const int ip1 = min(i + 1, M_ - 1);

        float fm[8], fp[8];
        unp8(ld_frag(Xp + (size_t)im1 * DHEAD + q * 8), fm);
        unp8(ld_frag(Xp + (size_t)ip1 * DHEAD + q * 8), fp);
        float sm = 0.f, s0 = 0.f, sp = 0.f;
        #pragma unroll
        for (int jj = 0; jj < 8; ++jj) {
            sm = fmaf(qf[jj], fm[jj], sm);
            s0 = fmaf(qf[jj], qf[jj], s0);
            sp = fmaf(qf[jj], fp[jj], sp);
        }
        sm += __shfl_xor(sm, 16, 64); sm += __shfl_xor(sm, 32, 64);
        s0 += __shfl_xor(s0, 16, 64); s0 += __shfl_xor(s0, 32, 64);
        sp += __shfl_xor(sp, 16, 64); sp += __shfl_xor(sp, 32, 64);

        const bool vOK = (i > 0), wOK = (i < M_ - 1);
        const float em = vOK ? exp2f(sm * SCL) : 1.0f;   // OOB -> score 0 -> e = 1
        const float e0 = exp2f(s0 * SCL);
        const float ep = wOK ? exp2f(sp * SCL) : 1.0f;
        const float vm = vOK ? em : 0.f;                  // value masked to 0
        const float vp = wOK ? ep : 0.f;
        const float inv = 1.0f / (Lp + em + e0 + ep);

        if (i < M_ - 1) {                                 // i = 1023 is padding
            const size_t rowb = ((size_t)bglob * S_ + 2 * i + rpar) * D_ + hh * DHEAD;
            #pragma unroll
            for (int h = 0; h < 2; ++h) {
                float xm[4], x0[4], xp4[4];
                {
                    uint2 u = *(const uint2*)(Xp + (size_t)im1 * DHEAD + h * 16 + q * 4);
                    bf2x2(u.x, xm[0], xm[1]); bf2x2(u.y, xm[2], xm[3]);
                }
                {
                    uint2 u = *(const uint2*)(Xp + (size_t)i * DHEAD + h * 16 + q * 4);
                    bf2x2(u.x, x0[0], x0[1]); bf2x2(u.y, x0[2], x0[3]);
                }
                {
                    uint2 u = *(const uint2*)(Xp + (size_t)ip1 * DHEAD + h * 16 + q * 4);
                    bf2x2(u.x, xp4[0], xp4[1]); bf2x2(u.y, xp4[2], xp4[3]);
                }
                float4 res;
                #pragma unroll
                for (int r = 0; r < 4; ++r) {
                    float v = Ot[h][r] + vm * xm[r] + e0 * x0[r] + vp * xp4[r];
                    ((float*)&res)[r] = v * inv;
                }
                *(float4*)(out + rowb + h * 16 + q * 4) = res;
            }
        }
    }
}

extern "C" void kernel_launch(void* const* d_in, const int* in_sizes, int n_in,
                              void* d_out, int out_size, void* d_ws, size_t ws_size,
                              hipStream_t stream) {
    const float* x    = (const float*)d_in[0];   // (4, 2046, 256) fp32
    const float* W    = (const float*)d_in[1];   // (256, 256) fp32
    const float* bias = (const float*)d_in[2];   // (256,) fp32
    uint16_t* qkv  = (uint16_t*)d_ws;                           // 4 MB
    uint16_t* qkvT = (uint16_t*)d_ws + (size_t)64 * M_ * DHEAD; // 4 MB
    uint16_t* Wt   = qkvT + (size_t)64 * M_ * DHEAD;            // 128 KB
    float* out = (float*)d_out;                  // (4, 2046, 256) fp32

    hipLaunchKernelGGL(wt_kernel,   dim3(64),   dim3(256), 0, stream, W, Wt);
    hipLaunchKernelGGL(proj_kernel, dim3(1024), dim3(256), 0, stream,
                       x, Wt, bias, qkv, qkvT);
    hipLaunchKernelGGL(attn_kernel, dim3(1024), dim3(256), 0, stream,
                       qkv, qkvT, out);
}

// Round 7
// 106.546 us; speedup vs baseline: 1.3219x; 1.3219x over previous
//
#include <hip/hip_runtime.h>
#include <stdint.h>
#include <stddef.h>

#define NB_HEAD 8
#define DHEAD   32
#define B_      4
#define S_      2046
#define N_      2048
#define M_      1024
#define D_      256

typedef __attribute__((ext_vector_type(8))) short short8;
typedef __attribute__((ext_vector_type(4))) float f32x4;

__device__ __forceinline__ void bf2x2(uint32_t u, float& lo, float& hi) {
    union { uint32_t i; float f; } a, b;
    a.i = u << 16;
    b.i = u & 0xffff0000u;
    lo = a.f; hi = b.f;
}
__device__ __forceinline__ float bf2f(uint16_t u) {
    union { uint32_t i; float f; } v; v.i = ((uint32_t)u) << 16; return v.f;
}
__device__ __forceinline__ uint16_t f2bf(float f) {
    union { float f; uint32_t i; } v; v.f = f;
    uint32_t u = v.i;
    u += 0x7fffu + ((u >> 16) & 1u);   // RNE
    return (uint16_t)(u >> 16);
}
__device__ __forceinline__ short8 ld_frag(const uint16_t* p) {
    union { uint4 u; short8 s; } v;
    v.u = *(const uint4*)p;
    return v.s;
}
__device__ __forceinline__ void unp8(short8 v, float* f) {
    union { short8 s; uint32_t u[4]; } x; x.s = v;
    #pragma unroll
    for (int k = 0; k < 4; ++k) bf2x2(x.u[k], f[2*k], f[2*k+1]);
}
// pack top-16 bits of two fp32 bit patterns into one dword (hi<<16 | lo)
__device__ __forceinline__ uint32_t pkbf(uint32_t hi, uint32_t lo) {
    return __builtin_amdgcn_perm(hi, lo, 0x07060302u);
}

// ---------------------------------------------------------------------------
// Kernel 0: Wt[c][k] = bf16(W[k][c]), one-shot 256x256 transpose.
// ---------------------------------------------------------------------------
__global__ __launch_bounds__(256) void wt_kernel(
    const float* __restrict__ W, uint16_t* __restrict__ Wt)
{
    const int t  = blockIdx.x * 256 + threadIdx.x;
    const int c  = t >> 6;
    const int k0 = (t & 63) * 4;
    union { uint16_t h[4]; uint2 u; } v;
    #pragma unroll
    for (int kk = 0; kk < 4; ++kk)
        v.h[kk] = f2bf(W[(size_t)(k0 + kk) * D_ + c]);
    *(uint2*)(Wt + (size_t)c * D_ + k0) = v.u;
}

// ---------------------------------------------------------------------------
// Kernel 1: MFMA projection, K-split for occupancy.
//   512 blocks = 128 row-groups(64) x 4 col-groups(64); 8 waves (512 thr):
//   wave (rp = w&3, kh = w>>2) does rows rp*16..+16, cols 64, k in
//   [kh*128, kh*128+128). fp32 partials merged in LDS, then the r5
//   dual-layout coalesced write phase (waves 0..3).
// ---------------------------------------------------------------------------
__global__ __launch_bounds__(512) void proj_kernel(
    const float* __restrict__ x, const uint16_t* __restrict__ Wt,
    const float* __restrict__ bias,
    uint16_t* __restrict__ qkv, uint16_t* __restrict__ qkvT)
{
    __shared__ float    mrgP[4][16][64];          // 16 KB
    __shared__ uint16_t Tl[64 * 80];              // 10 KB, stride 80 el
    const int tid  = threadIdx.x;
    const int w    = tid >> 6;
    const int lane = tid & 63;
    const int q    = lane >> 4;
    const int n16  = lane & 15;
    const int rp   = w & 3;
    const int kh   = w >> 2;
    const int rg   = blockIdx.x >> 2;
    const int cg   = blockIdx.x & 3;
    const int n0   = rg * 64;                     // 64 rows never straddle batch
    const int b    = n0 >> 11;
    const int nnb  = n0 & 2047;
    const int c0   = cg * 64;

    const f32x4 kZ = {0.f, 0.f, 0.f, 0.f};
    f32x4 acc[4];
    #pragma unroll
    for (int nt = 0; nt < 4; ++nt) acc[nt] = kZ;

    const int nrow = nnb + rp * 16 + n16;
    const bool ok  = (nrow < S_);
    const float* xrow = x + ((size_t)b * S_ + (ok ? nrow : 0)) * D_;

    #pragma unroll
    for (int kc = 0; kc < 4; ++kc) {
        const int k0 = kh * 128 + kc * 32;
        short8 A;
        if (ok) {
            const uint32_t* xp2 = (const uint32_t*)(xrow + k0 + q * 8);
            uint4 f0 = *(const uint4*)xp2;
            uint4 f1 = *(const uint4*)(xp2 + 4);
            union { uint32_t u[4]; short8 s; } av;
            av.u[0] = pkbf(f0.y + 0x8000u, f0.x + 0x8000u);
            av.u[1] = pkbf(f0.w + 0x8000u, f0.z + 0x8000u);
            av.u[2] = pkbf(f1.y + 0x8000u, f1.x + 0x8000u);
            av.u[3] = pkbf(f1.w + 0x8000u, f1.z + 0x8000u);
            A = av.s;
        } else {
            A = short8{0,0,0,0,0,0,0,0};
        }
        #pragma unroll
        for (int nt = 0; nt < 4; ++nt) {
            short8 Bf = ld_frag(Wt + (size_t)(c0 + nt * 16 + n16) * D_ + k0 + q * 8);
            acc[nt] = __builtin_amdgcn_mfma_f32_16x16x32_bf16(A, Bf, acc[nt], 0, 0, 0);
        }
    }

    // ---- merge K-halves ----
    if (kh == 1) {
        #pragma unroll
        for (int nt = 0; nt < 4; ++nt)
            #pragma unroll
            for (int r = 0; r < 4; ++r)
                mrgP[rp][nt * 4 + r][lane] = acc[nt][r];
    }
    __syncthreads();
    if (kh == 0) {
        #pragma unroll
        for (int nt = 0; nt < 4; ++nt) {
            const float bv = bias[c0 + nt * 16 + n16];
            #pragma unroll
            for (int r = 0; r < 4; ++r) {
                float v = acc[nt][r] + mrgP[rp][nt * 4 + r][lane] + bv;
                Tl[(rp * 16 + q * 4 + r) * 80 + nt * 16 + n16] = f2bf(v);
            }
        }
    }
    __syncthreads();

    // ---- write phase (waves 0..3): wave w owns (hloc = w>>1, rr = w&1) ----
    if (w < 4) {
        const int hloc = w >> 1, rr = w & 1;
        const int hglob = (c0 >> 5) + hloc;
        const int pglob = (b * NB_HEAD + hglob) * 2 + rr;
        const int ibase = nnb >> 1;               // multiple of 32
        uint16_t* qk = qkv  + (size_t)pglob * (M_ * DHEAD);
        uint16_t* qt = qkvT + (size_t)pglob * (M_ * DHEAD);

        {   // qkv: lane -> (ii = lane>>1, d0 = (lane&1)*16): 32 B/lane
            const int ii = lane >> 1, d0 = (lane & 1) * 16;
            const uint4* src = (const uint4*)(Tl + (2 * ii + rr) * 80 + hloc * 32 + d0);
            uint4 v0 = src[0], v1 = src[1];
            uint4* dst = (uint4*)(qk + (size_t)(ibase + ii) * DHEAD + d0);
            dst[0] = v0; dst[1] = v1;
        }
        {   // qkvT: lane -> (d = lane>>1, ph = (lane&1)*16): 32 B/lane
            const int d = lane >> 1, ph = (lane & 1) * 16;
            uint32_t pk[8];
            #pragma unroll
            for (int t = 0; t < 16; ++t) {
                const int pos = ph + t;
                const int il = (((pos >> 2) & 1) << 4) | (((pos >> 3) & 3) << 2) | (pos & 3);
                const uint32_t vv = Tl[(2 * il + rr) * 80 + hloc * 32 + d];
                if (t & 1) pk[t >> 1] |= vv << 16; else pk[t >> 1] = vv;
            }
            uint4* dst = (uint4*)(qt + (size_t)d * M_ + ibase + ph);
            dst[0] = *(uint4*)&pk[0];
            dst[1] = *(uint4*)&pk[4];
        }
    }
}

// ---------------------------------------------------------------------------
// Kernel 2: MFMA flash attention, transposed scores, j-split for occupancy.
//   512 blocks = 64 problems x 8 chunks(128 rows); 8 waves (512 thr):
//   wave (rowgrp = w&3, jh = w>>2) does rows rowgrp*32..+32 over j-half
//   [jh*512, +512). Fixed-max softmax => numerators independent, L additive;
//   partner partials (O^T, L) merged via LDS + one barrier.
//   Scores: St = mfma(A = X_j frag, B = Q frag); PV: O^T = mfma(A = qkvT frag,
//   B = P^T packed in-register). XCD swizzle clusters a problem per XCD.
// ---------------------------------------------------------------------------
__global__ __launch_bounds__(512) void attn_kernel(
    const uint16_t* __restrict__ qkv, const uint16_t* __restrict__ qkvT,
    float* __restrict__ out)
{
    const float SCL = 0.17677669529663687f * 1.4426950408889634f; // 1/sqrt(32)*log2(e)
    __shared__ float mrg[4][18][64];              // 18 KB merge buffer
    const int tid  = threadIdx.x;
    const int w    = tid >> 6;
    const int lane = tid & 63;
    const int q    = lane >> 4;
    const int n16  = lane & 15;
    const int rowgrp = w & 3;
    const int jh     = w >> 2;
    const int bid  = blockIdx.x;
    const int p     = ((bid & 7) << 3) | ((bid >> 3) & 7);
    const int chunk = bid >> 6;                   // 0..7
    const uint16_t* Xp = qkv  + (size_t)p * (M_ * DHEAD);
    const uint16_t* Xt = qkvT + (size_t)p * (M_ * DHEAD);

    const int rbase = chunk * 128 + rowgrp * 32;
    const int jb0   = jh * 512;
    const f32x4 kZ = {0.f, 0.f, 0.f, 0.f};

    short8 Q0 = ld_frag(Xp + (size_t)(rbase + n16) * DHEAD + q * 8);
    short8 Q1 = ld_frag(Xp + (size_t)(rbase + 16 + n16) * DHEAD + q * 8);

    f32x4 Ot[2][2];                    // [it][h]: O^T[d = h*16+q*4+r][i = it*16+n16]
    #pragma unroll
    for (int it = 0; it < 2; ++it) { Ot[it][0] = kZ; Ot[it][1] = kZ; }
    float Lp[2] = {0.f, 0.f};

    short8 Bf[4], XF[2][2];
    #pragma unroll
    for (int g = 0; g < 4; ++g)
        Bf[g] = ld_frag(Xp + (size_t)(jb0 + g * 16 + n16) * DHEAD + q * 8);
    #pragma unroll
    for (int h = 0; h < 2; ++h)
        #pragma unroll
        for (int c = 0; c < 2; ++c)
            XF[h][c] = ld_frag(Xt + (size_t)(h * 16 + n16) * M_ + jb0 + c * 32 + q * 8);

    for (int tile = 0; tile < 8; ++tile) {
        f32x4 S0[4], S1[4];
        #pragma unroll
        for (int g = 0; g < 4; ++g) {
            S0[g] = __builtin_amdgcn_mfma_f32_16x16x32_bf16(Bf[g], Q0, kZ, 0, 0, 0);
            S1[g] = __builtin_amdgcn_mfma_f32_16x16x32_bf16(Bf[g], Q1, kZ, 0, 0, 0);
        }
        // prefetch next tile (wrap within this wave's j-half)
        const int jb2 = jb0 + ((tile + 1) & 7) * 64;
        short8 Bn[4], XFn[2][2];
        #pragma unroll
        for (int g = 0; g < 4; ++g)
            Bn[g] = ld_frag(Xp + (size_t)(jb2 + g * 16 + n16) * DHEAD + q * 8);
        #pragma unroll
        for (int h = 0; h < 2; ++h)
            #pragma unroll
            for (int c = 0; c < 2; ++c)
                XFn[h][c] = ld_frag(Xt + (size_t)(h * 16 + n16) * M_ + jb2 + c * 32 + q * 8);

        #pragma unroll
        for (int it = 0; it < 2; ++it) {
            f32x4* S = it ? S1 : S0;
            uint32_t t[4][4];
            float rs = 0.f;
            #pragma unroll
            for (int g = 0; g < 4; ++g)
                #pragma unroll
                for (int r = 0; r < 4; ++r) {
                    float e = exp2f(S[g][r] * SCL);
                    uint32_t tt = (__float_as_uint(e) + 0x8000u) & 0xffff0000u;
                    t[g][r] = tt;
                    rs += __uint_as_float(tt);    // L consistent with packed P
                }
            Lp[it] += rs;
            #pragma unroll
            for (int c = 0; c < 2; ++c) {
                union { uint32_t u[4]; short8 s; } bp;
                bp.u[0] = pkbf(t[2*c][1],   t[2*c][0]);
                bp.u[1] = pkbf(t[2*c][3],   t[2*c][2]);
                bp.u[2] = pkbf(t[2*c+1][1], t[2*c+1][0]);
                bp.u[3] = pkbf(t[2*c+1][3], t[2*c+1][2]);
                Ot[it][0] = __builtin_amdgcn_mfma_f32_16x16x32_bf16(XF[0][c], bp.s, Ot[it][0], 0, 0, 0);
                Ot[it][1] = __builtin_amdgcn_mfma_f32_16x16x32_bf16(XF[1][c], bp.s, Ot[it][1], 0, 0, 0);
            }
        }
        #pragma unroll
        for (int g = 0; g < 4; ++g) Bf[g] = Bn[g];
        #pragma unroll
        for (int h = 0; h < 2; ++h) {
            XF[h][0] = XFn[h][0]; XF[h][1] = XFn[h][1];
        }
    }

    // ---- reduce L over the 4 q-quads (lane bits 4,5) ----
    #pragma unroll
    for (int it = 0; it < 2; ++it) {
        Lp[it] += __shfl_xor(Lp[it], 16, 64);
        Lp[it] += __shfl_xor(Lp[it], 32, 64);
    }

    // ---- merge the two j-halves ----
    if (jh == 1) {
        #pragma unroll
        for (int it = 0; it < 2; ++it)
            #pragma unroll
            for (int h = 0; h < 2; ++h)
                #pragma unroll
                for (int r = 0; r < 4; ++r)
                    mrg[rowgrp][it * 8 + h * 4 + r][lane] = Ot[it][h][r];
        mrg[rowgrp][16][lane] = Lp[0];
        mrg[rowgrp][17][lane] = Lp[1];
    }
    __syncthreads();
    if (jh == 1) return;

    #pragma unroll
    for (int it = 0; it < 2; ++it) {
        #pragma unroll
        for (int h = 0; h < 2; ++h)
            #pragma unroll
            for (int r = 0; r < 4; ++r)
                Ot[it][h][r] += mrg[rowgrp][it * 8 + h * 4 + r][lane];
        Lp[it] += mrg[rowgrp][16 + it][lane];
    }

    // ---- epilogue: 3 local extras per row + normalize + store ----
    const int rpar  = p & 1;
    const int hh    = (p >> 1) & 7;
    const int bglob = p >> 4;

    #pragma unroll
    for (int it = 0; it < 2; ++it) {
        const int i = rbase + it * 16 + n16;
        float qf[8];
        unp8(it ? Q1 : Q0, qf);
        const int im1 = max(i - 1, 0);
        const int ip1 = min(i + 1, M_ - 1);

        float fm[8], fp[8];
        unp8(ld_frag(Xp + (size_t)im1 * DHEAD + q * 8), fm);
        unp8(ld_frag(Xp + (size_t)ip1 * DHEAD + q * 8), fp);
        float sm = 0.f, s0 = 0.f, sp = 0.f;
        #pragma unroll
        for (int jj = 0; jj < 8; ++jj) {
            sm = fmaf(qf[jj], fm[jj], sm);
            s0 = fmaf(qf[jj], qf[jj], s0);
            sp = fmaf(qf[jj], fp[jj], sp);
        }
        sm += __shfl_xor(sm, 16, 64); sm += __shfl_xor(sm, 32, 64);
        s0 += __shfl_xor(s0, 16, 64); s0 += __shfl_xor(s0, 32, 64);
        sp += __shfl_xor(sp, 16, 64); sp += __shfl_xor(sp, 32, 64);

        const bool vOK = (i > 0), wOK = (i < M_ - 1);
        const float em = vOK ? exp2f(sm * SCL) : 1.0f;   // OOB -> score 0 -> e = 1
        const float e0 = exp2f(s0 * SCL);
        const float ep = wOK ? exp2f(sp * SCL) : 1.0f;
        const float vm = vOK ? em : 0.f;                  // value masked to 0
        const float vp = wOK ? ep : 0.f;
        const float inv = 1.0f / (Lp[it] + em + e0 + ep);

        if (i < M_ - 1) {                                 // i = 1023 is padding
            const size_t rowb = ((size_t)bglob * S_ + 2 * i + rpar) * D_ + hh * DHEAD;
            #pragma unroll
            for (int h = 0; h < 2; ++h) {
                float xm[4], x0[4], xp4[4];
                {
                    uint2 u = *(const uint2*)(Xp + (size_t)im1 * DHEAD + h * 16 + q * 4);
                    bf2x2(u.x, xm[0], xm[1]); bf2x2(u.y, xm[2], xm[3]);
                }
                {
                    uint2 u = *(const uint2*)(Xp + (size_t)i * DHEAD + h * 16 + q * 4);
                    bf2x2(u.x, x0[0], x0[1]); bf2x2(u.y, x0[2], x0[3]);
                }
                {
                    uint2 u = *(const uint2*)(Xp + (size_t)ip1 * DHEAD + h * 16 + q * 4);
                    bf2x2(u.x, xp4[0], xp4[1]); bf2x2(u.y, xp4[2], xp4[3]);
                }
                float4 res;
                #pragma unroll
                for (int r = 0; r < 4; ++r) {
                    float v = Ot[it][h][r] + vm * xm[r] + e0 * x0[r] + vp * xp4[r];
                    ((float*)&res)[r] = v * inv;
                }
                *(float4*)(out + rowb + h * 16 + q * 4) = res;
            }
        }
    }
}

extern "C" void kernel_launch(void* const* d_in, const int* in_sizes, int n_in,
                              void* d_out, int out_size, void* d_ws, size_t ws_size,
                              hipStream_t stream) {
    const float* x    = (const float*)d_in[0];   // (4, 2046, 256) fp32
    const float* W    = (const float*)d_in[1];   // (256, 256) fp32
    const float* bias = (const float*)d_in[2];   // (256,) fp32
    uint16_t* qkv  = (uint16_t*)d_ws;                           // 4 MB
    uint16_t* qkvT = (uint16_t*)d_ws + (size_t)64 * M_ * DHEAD; // 4 MB
    uint16_t* Wt   = qkvT + (size_t)64 * M_ * DHEAD;            // 128 KB
    float* out = (float*)d_out;                  // (4, 2046, 256) fp32

    hipLaunchKernelGGL(wt_kernel,   dim3(64),  dim3(256), 0, stream, W, Wt);
    hipLaunchKernelGGL(proj_kernel, dim3(512), dim3(512), 0, stream,
                       x, Wt, bias, qkv, qkvT);
    hipLaunchKernelGGL(attn_kernel, dim3(512), dim3(512), 0, stream,
                       qkv, qkvT, out);
}

// Round 8
// 97.503 us; speedup vs baseline: 1.4445x; 1.0927x over previous
//
#include <hip/hip_runtime.h>
#include <stdint.h>
#include <stddef.h>

#define NB_HEAD 8
#define DHEAD   32
#define B_      4
#define S_      2046
#define N_      2048
#define M_      1024
#define D_      256

#define WT_S    264                   // WtL row stride (elements): 528 B, 16-B aligned, low-conflict

typedef __attribute__((ext_vector_type(8))) short short8;
typedef __attribute__((ext_vector_type(4))) float f32x4;

__device__ __forceinline__ void bf2x2(uint32_t u, float& lo, float& hi) {
    union { uint32_t i; float f; } a, b;
    a.i = u << 16;
    b.i = u & 0xffff0000u;
    lo = a.f; hi = b.f;
}
__device__ __forceinline__ uint16_t f2bf(float f) {
    union { float f; uint32_t i; } v; v.f = f;
    uint32_t u = v.i;
    u += 0x7fffu + ((u >> 16) & 1u);   // RNE
    return (uint16_t)(u >> 16);
}
__device__ __forceinline__ short8 ld_frag(const uint16_t* p) {
    union { uint4 u; short8 s; } v;
    v.u = *(const uint4*)p;
    return v.s;
}
__device__ __forceinline__ void unp8(short8 v, float* f) {
    union { short8 s; uint32_t u[4]; } x; x.s = v;
    #pragma unroll
    for (int k = 0; k < 4; ++k) bf2x2(x.u[k], f[2*k], f[2*k+1]);
}
// pack top-16 bits of two fp32 bit patterns into one dword (hi<<16 | lo)
__device__ __forceinline__ uint32_t pkbf(uint32_t hi, uint32_t lo) {
    return __builtin_amdgcn_perm(hi, lo, 0x07060302u);
}

// ---------------------------------------------------------------------------
// Kernel 1: MFMA projection, K-split, W transposed per-block into LDS
//   (wt kernel folded in: no ordering dep, ~64 KB L2 reads per block).
//   512 blocks = 128 row-groups(64) x 4 col-groups(64); 8 waves (512 thr):
//   wave (rp = w&3, kh = w>>2): rows rp*16..+16, k in [kh*128, +128).
//   fp32 partials merged in LDS, then dual-layout coalesced write phase.
// ---------------------------------------------------------------------------
__global__ __launch_bounds__(512) void proj_kernel(
    const float* __restrict__ x, const float* __restrict__ W,
    const float* __restrict__ bias,
    uint16_t* __restrict__ qkv, uint16_t* __restrict__ qkvT)
{
    __shared__ __align__(16) uint16_t WtL[64 * WT_S]; // 33 KB: Wt[cloc][k]
    __shared__ float    mrgP[4][16][64];              // 16 KB
    __shared__ uint16_t Tl[64 * 80];                  // 10 KB, stride 80 el
    const int tid  = threadIdx.x;
    const int w    = tid >> 6;
    const int lane = tid & 63;
    const int q    = lane >> 4;
    const int n16  = lane & 15;
    const int rp   = w & 3;
    const int kh   = w >> 2;
    const int rg   = blockIdx.x >> 2;
    const int cg   = blockIdx.x & 3;
    const int n0   = rg * 64;                     // 64 rows never straddle batch
    const int b    = n0 >> 11;
    const int nnb  = n0 & 2047;
    const int c0   = cg * 64;

    // ---- phase A: transpose this block's 64 W-columns into LDS ----
    {
        const uint32_t* Wb = (const uint32_t*)(W + c0 + lane);
        #pragma unroll 4
        for (int s = 0; s < 16; ++s) {
            const int k0 = 2 * (w * 16 + s);
            uint32_t a = Wb[(size_t)k0 * D_];
            uint32_t c = Wb[(size_t)(k0 + 1) * D_];
            *(uint32_t*)(WtL + (size_t)lane * WT_S + k0) =
                pkbf(c + 0x8000u, a + 0x8000u);
        }
    }

    const f32x4 kZ = {0.f, 0.f, 0.f, 0.f};
    f32x4 acc[4];
    #pragma unroll
    for (int nt = 0; nt < 4; ++nt) acc[nt] = kZ;

    const int nrow = nnb + rp * 16 + n16;
    const bool ok  = (nrow < S_);
    const float* xrow = x + ((size_t)b * S_ + (ok ? nrow : 0)) * D_;

    __syncthreads();

    #pragma unroll
    for (int kc = 0; kc < 4; ++kc) {
        const int k0 = kh * 128 + kc * 32;
        short8 A;
        if (ok) {
            const uint32_t* xp2 = (const uint32_t*)(xrow + k0 + q * 8);
            uint4 f0 = *(const uint4*)xp2;
            uint4 f1 = *(const uint4*)(xp2 + 4);
            union { uint32_t u[4]; short8 s; } av;
            av.u[0] = pkbf(f0.y + 0x8000u, f0.x + 0x8000u);
            av.u[1] = pkbf(f0.w + 0x8000u, f0.z + 0x8000u);
            av.u[2] = pkbf(f1.y + 0x8000u, f1.x + 0x8000u);
            av.u[3] = pkbf(f1.w + 0x8000u, f1.z + 0x8000u);
            A = av.s;
        } else {
            A = short8{0,0,0,0,0,0,0,0};
        }
        #pragma unroll
        for (int nt = 0; nt < 4; ++nt) {
            short8 Bf = ld_frag(WtL + (size_t)(nt * 16 + n16) * WT_S + k0 + q * 8);
            acc[nt] = __builtin_amdgcn_mfma_f32_16x16x32_bf16(A, Bf, acc[nt], 0, 0, 0);
        }
    }

    // ---- merge K-halves ----
    if (kh == 1) {
        #pragma unroll
        for (int nt = 0; nt < 4; ++nt)
            #pragma unroll
            for (int r = 0; r < 4; ++r)
                mrgP[rp][nt * 4 + r][lane] = acc[nt][r];
    }
    __syncthreads();
    if (kh == 0) {
        #pragma unroll
        for (int nt = 0; nt < 4; ++nt) {
            const float bv = bias[c0 + nt * 16 + n16];
            #pragma unroll
            for (int r = 0; r < 4; ++r) {
                float v = acc[nt][r] + mrgP[rp][nt * 4 + r][lane] + bv;
                Tl[(rp * 16 + q * 4 + r) * 80 + nt * 16 + n16] = f2bf(v);
            }
        }
    }
    __syncthreads();

    // ---- write phase (waves 0..3): wave w owns (hloc = w>>1, rr = w&1) ----
    if (w < 4) {
        const int hloc = w >> 1, rr = w & 1;
        const int hglob = (c0 >> 5) + hloc;
        const int pglob = (b * NB_HEAD + hglob) * 2 + rr;
        const int ibase = nnb >> 1;               // multiple of 32
        uint16_t* qk = qkv  + (size_t)pglob * (M_ * DHEAD);
        uint16_t* qt = qkvT + (size_t)pglob * (M_ * DHEAD);

        {   // qkv: lane -> (ii = lane>>1, d0 = (lane&1)*16): 32 B/lane
            const int ii = lane >> 1, d0 = (lane & 1) * 16;
            const uint4* src = (const uint4*)(Tl + (2 * ii + rr) * 80 + hloc * 32 + d0);
            uint4 v0 = src[0], v1 = src[1];
            uint4* dst = (uint4*)(qk + (size_t)(ibase + ii) * DHEAD + d0);
            dst[0] = v0; dst[1] = v1;
        }
        {   // qkvT: lane -> (d = lane>>1, ph = (lane&1)*16): 32 B/lane
            const int d = lane >> 1, ph = (lane & 1) * 16;
            uint32_t pk[8];
            #pragma unroll
            for (int t = 0; t < 16; ++t) {
                const int pos = ph + t;
                const int il = (((pos >> 2) & 1) << 4) | (((pos >> 3) & 3) << 2) | (pos & 3);
                const uint32_t vv = Tl[(2 * il + rr) * 80 + hloc * 32 + d];
                if (t & 1) pk[t >> 1] |= vv << 16; else pk[t >> 1] = vv;
            }
            uint4* dst = (uint4*)(qt + (size_t)d * M_ + ibase + ph);
            dst[0] = *(uint4*)&pk[0];
            dst[1] = *(uint4*)&pk[4];
        }
    }
}

// ---------------------------------------------------------------------------
// Kernel 2: MFMA flash attention, transposed scores, j-split, VALU diet:
//   - Q frags pre-scaled by SCL (bf16) -> no per-score multiply
//   - P truncated to bf16 via v_perm pack (no rounding add)
//   - L via mfma(ones, P^T, Lacc): exact sum of the bf16 P actually used,
//     replicated across all lanes of the 16-lane group -> no shuffles.
//   512 blocks = 64 problems x 8 chunks(128 rows); 8 waves (512 thr):
//   wave (rowgrp = w&3, jh = w>>2): rows rowgrp*32..+32, j in [jh*512, +512).
//   XCD swizzle clusters a problem's blocks on one XCD.
// ---------------------------------------------------------------------------
__global__ __launch_bounds__(512) void attn_kernel(
    const uint16_t* __restrict__ qkv, const uint16_t* __restrict__ qkvT,
    float* __restrict__ out)
{
    const float SCL = 0.17677669529663687f * 1.4426950408889634f; // 1/sqrt(32)*log2(e)
    __shared__ float mrg[4][18][64];              // 18 KB merge buffer
    const int tid  = threadIdx.x;
    const int w    = tid >> 6;
    const int lane = tid & 63;
    const int q    = lane >> 4;
    const int n16  = lane & 15;
    const int rowgrp = w & 3;
    const int jh     = w >> 2;
    const int bid  = blockIdx.x;
    const int p     = ((bid & 7) << 3) | ((bid >> 3) & 7);
    const int chunk = bid >> 6;                   // 0..7
    const uint16_t* Xp = qkv  + (size_t)p * (M_ * DHEAD);
    const uint16_t* Xt = qkvT + (size_t)p * (M_ * DHEAD);

    const int rbase = chunk * 128 + rowgrp * 32;
    const int jb0   = jh * 512;
    const f32x4 kZ = {0.f, 0.f, 0.f, 0.f};
    short8 ONES;
    #pragma unroll
    for (int k = 0; k < 8; ++k) ONES[k] = (short)0x3F80;   // bf16 1.0

    short8 Q0 = ld_frag(Xp + (size_t)(rbase + n16) * DHEAD + q * 8);
    short8 Q1 = ld_frag(Xp + (size_t)(rbase + 16 + n16) * DHEAD + q * 8);

    // pre-scaled Q frags (one-time): Qs = bf16(SCL * q)
    short8 Q0s, Q1s;
    {
        float f0[8], f1[8];
        unp8(Q0, f0); unp8(Q1, f1);
        union { uint16_t h[8]; short8 s; } a, b;
        #pragma unroll
        for (int k = 0; k < 8; ++k) {
            a.h[k] = f2bf(f0[k] * SCL);
            b.h[k] = f2bf(f1[k] * SCL);
        }
        Q0s = a.s; Q1s = b.s;
    }

    f32x4 Ot[2][2];                    // [it][h]: O^T[d = h*16+q*4+r][i = it*16+n16]
    #pragma unroll
    for (int it = 0; it < 2; ++it) { Ot[it][0] = kZ; Ot[it][1] = kZ; }
    f32x4 Lacc[2] = {kZ, kZ};          // per-it MFMA row-sum of P^T

    short8 Bf[4], XF[2][2];
    #pragma unroll
    for (int g = 0; g < 4; ++g)
        Bf[g] = ld_frag(Xp + (size_t)(jb0 + g * 16 + n16) * DHEAD + q * 8);
    #pragma unroll
    for (int h = 0; h < 2; ++h)
        #pragma unroll
        for (int c = 0; c < 2; ++c)
            XF[h][c] = ld_frag(Xt + (size_t)(h * 16 + n16) * M_ + jb0 + c * 32 + q * 8);

    for (int tile = 0; tile < 8; ++tile) {
        f32x4 S0[4], S1[4];
        #pragma unroll
        for (int g = 0; g < 4; ++g) {
            S0[g] = __builtin_amdgcn_mfma_f32_16x16x32_bf16(Bf[g], Q0s, kZ, 0, 0, 0);
            S1[g] = __builtin_amdgcn_mfma_f32_16x16x32_bf16(Bf[g], Q1s, kZ, 0, 0, 0);
        }
        // prefetch next tile (wrap within this wave's j-half)
        const int jb2 = jb0 + ((tile + 1) & 7) * 64;
        short8 Bn[4], XFn[2][2];
        #pragma unroll
        for (int g = 0; g < 4; ++g)
            Bn[g] = ld_frag(Xp + (size_t)(jb2 + g * 16 + n16) * DHEAD + q * 8);
        #pragma unroll
        for (int h = 0; h < 2; ++h)
            #pragma unroll
            for (int c = 0; c < 2; ++c)
                XFn[h][c] = ld_frag(Xt + (size_t)(h * 16 + n16) * M_ + jb2 + c * 32 + q * 8);

        #pragma unroll
        for (int it = 0; it < 2; ++it) {
            f32x4* S = it ? S1 : S0;
            uint32_t t[4][4];
            #pragma unroll
            for (int g = 0; g < 4; ++g)
                #pragma unroll
                for (int r = 0; r < 4; ++r)
                    t[g][r] = __float_as_uint(exp2f(S[g][r]));   // S pre-scaled
            #pragma unroll
            for (int c = 0; c < 2; ++c) {
                union { uint32_t u[4]; short8 s; } bp;           // truncating pack
                bp.u[0] = pkbf(t[2*c][1],   t[2*c][0]);
                bp.u[1] = pkbf(t[2*c][3],   t[2*c][2]);
                bp.u[2] = pkbf(t[2*c+1][1], t[2*c+1][0]);
                bp.u[3] = pkbf(t[2*c+1][3], t[2*c+1][2]);
                Ot[it][0] = __builtin_amdgcn_mfma_f32_16x16x32_bf16(XF[0][c], bp.s, Ot[it][0], 0, 0, 0);
                Ot[it][1] = __builtin_amdgcn_mfma_f32_16x16x32_bf16(XF[1][c], bp.s, Ot[it][1], 0, 0, 0);
                Lacc[it]  = __builtin_amdgcn_mfma_f32_16x16x32_bf16(ONES,     bp.s, Lacc[it],  0, 0, 0);
            }
        }
        #pragma unroll
        for (int g = 0; g < 4; ++g) Bf[g] = Bn[g];
        #pragma unroll
        for (int h = 0; h < 2; ++h) {
            XF[h][0] = XFn[h][0]; XF[h][1] = XFn[h][1];
        }
    }

    // Lacc rows are identical (A = ones) -> every lane already holds
    // L_partial for its column i; no cross-lane reduce needed.
    float Lp[2] = {Lacc[0][0], Lacc[1][0]};

    // ---- merge the two j-halves ----
    if (jh == 1) {
        #pragma unroll
        for (int it = 0; it < 2; ++it)
            #pragma unroll
            for (int h = 0; h < 2; ++h)
                #pragma unroll
                for (int r = 0; r < 4; ++r)
                    mrg[rowgrp][it * 8 + h * 4 + r][lane] = Ot[it][h][r];
        mrg[rowgrp][16][lane] = Lp[0];
        mrg[rowgrp][17][lane] = Lp[1];
    }
    __syncthreads();
    if (jh == 1) return;

    #pragma unroll
    for (int it = 0; it < 2; ++it) {
        #pragma unroll
        for (int h = 0; h < 2; ++h)
            #pragma unroll
            for (int r = 0; r < 4; ++r)
                Ot[it][h][r] += mrg[rowgrp][it * 8 + h * 4 + r][lane];
        Lp[it] += mrg[rowgrp][16 + it][lane];
    }

    // ---- epilogue: 3 local extras per row + normalize + store ----
    const int rpar  = p & 1;
    const int hh    = (p >> 1) & 7;
    const int bglob = p >> 4;

    #pragma unroll
    for (int it = 0; it < 2; ++it) {
        const int i = rbase + it * 16 + n16;
        float qs[8], qr[8];
        unp8(it ? Q1s : Q0s, qs);
        unp8(it ? Q1  : Q0,  qr);
        const int im1 = max(i - 1, 0);
        const int ip1 = min(i + 1, M_ - 1);

        float fm[8], fp[8];
        unp8(ld_frag(Xp + (size_t)im1 * DHEAD + q * 8), fm);
        unp8(ld_frag(Xp + (size_t)ip1 * DHEAD + q * 8), fp);
        float sm = 0.f, s0 = 0.f, sp = 0.f;
        #pragma unroll
        for (int jj = 0; jj < 8; ++jj) {
            sm = fmaf(qs[jj], fm[jj], sm);      // = SCL * (q . x_{i-1}), pre-scaled
            s0 = fmaf(qs[jj], qr[jj], s0);      // = SCL * |q|^2
            sp = fmaf(qs[jj], fp[jj], sp);
        }
        sm += __shfl_xor(sm, 16, 64); sm += __shfl_xor(sm, 32, 64);
        s0 += __shfl_xor(s0, 16, 64); s0 += __shfl_xor(s0, 32, 64);
        sp += __shfl_xor(sp, 16, 64); sp += __shfl_xor(sp, 32, 64);

        const bool vOK = (i > 0), wOK = (i < M_ - 1);
        const float em = vOK ? exp2f(sm) : 1.0f;   // OOB -> score 0 -> e = 1
        const float e0 = exp2f(s0);
        const float ep = wOK ? exp2f(sp) : 1.0f;
        const float vm = vOK ? em : 0.f;           // value masked to 0
        const float vp = wOK ? ep : 0.f;
        const float inv = 1.0f / (Lp[it] + em + e0 + ep);

        if (i < M_ - 1) {                          // i = 1023 is padding
            const size_t rowb = ((size_t)bglob * S_ + 2 * i + rpar) * D_ + hh * DHEAD;
            #pragma unroll
            for (int h = 0; h < 2; ++h) {
                float xm[4], x0[4], xp4[4];
                {
                    uint2 u = *(const uint2*)(Xp + (size_t)im1 * DHEAD + h * 16 + q * 4);
                    bf2x2(u.x, xm[0], xm[1]); bf2x2(u.y, xm[2], xm[3]);
                }
                {
                    uint2 u = *(const uint2*)(Xp + (size_t)i * DHEAD + h * 16 + q * 4);
                    bf2x2(u.x, x0[0], x0[1]); bf2x2(u.y, x0[2], x0[3]);
                }
                {
                    uint2 u = *(const uint2*)(Xp + (size_t)ip1 * DHEAD + h * 16 + q * 4);
                    bf2x2(u.x, xp4[0], xp4[1]); bf2x2(u.y, xp4[2], xp4[3]);
                }
                float4 res;
                #pragma unroll
                for (int r = 0; r < 4; ++r) {
                    float v = Ot[it][h][r] + vm * xm[r] + e0 * x0[r] + vp * xp4[r];
                    ((float*)&res)[r] = v * inv;
                }
                *(float4*)(out + rowb + h * 16 + q * 4) = res;
            }
        }
    }
}

extern "C" void kernel_launch(void* const* d_in, const int* in_sizes, int n_in,
                              void* d_out, int out_size, void* d_ws, size_t ws_size,
                              hipStream_t stream) {
    const float* x    = (const float*)d_in[0];   // (4, 2046, 256) fp32
    const float* W    = (const float*)d_in[1];   // (256, 256) fp32
    const float* bias = (const float*)d_in[2];   // (256,) fp32
    uint16_t* qkv  = (uint16_t*)d_ws;                           // 4 MB
    uint16_t* qkvT = (uint16_t*)d_ws + (size_t)64 * M_ * DHEAD; // 4 MB
    float* out = (float*)d_out;                  // (4, 2046, 256) fp32

    hipLaunchKernelGGL(proj_kernel, dim3(512), dim3(512), 0, stream,
                       x, W, bias, qkv, qkvT);
    hipLaunchKernelGGL(attn_kernel, dim3(512), dim3(512), 0, stream,
                       qkv, qkvT, out);
}